// Round 18
// baseline (812.205 us; speedup 1.0000x reference)
//
#include <hip/hip_runtime.h>
#include <hip/hip_bf16.h>
#include <cstdint>

#define HID 128
#define BSHIFT 11   // 2048 nodes per bucket

typedef short short8 __attribute__((ext_vector_type(8)));
typedef float f32x4 __attribute__((ext_vector_type(4)));

__device__ __forceinline__ unsigned pack_bf16(float a, float b)
{
    __hip_bfloat16 ha = __float2bfloat16(a);
    __hip_bfloat16 hb = __float2bfloat16(b);
    unsigned short ua = *reinterpret_cast<unsigned short*>(&ha);
    unsigned short ub = *reinterpret_cast<unsigned short*>(&hb);
    return (unsigned)ua | ((unsigned)ub << 16);
}

__device__ __forceinline__ float bf16_lo(unsigned u)
{
    unsigned v = u << 16;
    return *reinterpret_cast<float*>(&v);
}
__device__ __forceinline__ float bf16_hi(unsigned u)
{
    unsigned v = u & 0xffff0000u;
    return *reinterpret_cast<float*>(&v);
}

__device__ __forceinline__ void split8(const float* v, short8& h, short8& l)
{
    #pragma unroll
    for (int j = 0; j < 8; ++j) {
        unsigned bits = __float_as_uint(v[j]);
        h[j] = (short)(bits >> 16);
        unsigned hb = bits & 0xffff0000u;
        float lof = v[j] - __uint_as_float(hb);
        l[j] = (short)(__float_as_uint(lof) >> 16);
    }
}

__device__ __forceinline__ short8 frag_ld(const short* __restrict__ base, int tile, int lane)
{
    return *reinterpret_cast<const short8*>(base + (((size_t)tile * 64 + lane) << 3));
}

__device__ __forceinline__ int lds_addr(int row, int unit)
{
    return row * 256 + ((unit ^ (row & 7)) << 4);
}

// ---------------------------------------------------------------------------
// One-shot weight conversion
// ---------------------------------------------------------------------------
__global__ void convert_w_kernel(
    const float* W0, const float* W1, const float* W2,
    const float* W3, const float* W4, const float* W5,
    short* H0, short* L0, short* H1, short* L1, short* H2, short* L2,
    short* H3, short* L3, short* H4, short* L4, short* H5, short* L5)
{
    int job = blockIdx.y;
    const float* W; short* H; short* L; int K, C;
    switch (job) {
        case 0: W = W0; H = H0; L = L0; K = 768; C = 32;  break;
        case 1: W = W1; H = H1; L = L1; K = 768; C = 32;  break;
        case 2: W = W2; H = H2; L = L2; K = 128; C = 128; break;
        case 3: W = W3; H = H3; L = L3; K = 128; C = 128; break;
        case 4: W = W4; H = H4; L = L4; K = 128; C = 128; break;
        default: W = W5; H = H5; L = L5; K = 128; C = 128; break;
    }
    int NT = C >> 4;
    int rows = (K >> 5) * NT * 64;
    int r = blockIdx.x * blockDim.x + threadIdx.x;
    if (r >= rows) return;
    int lane = r & 63;
    int tile = r >> 6;
    int c = (tile % NT) * 16 + (lane & 15);
    int kbase = (tile / NT) * 32 + ((lane >> 4) & 3) * 8;
    float v[8];
    #pragma unroll
    for (int j = 0; j < 8; ++j) v[j] = W[(size_t)(kbase + j) * C + c];
    short8 h, l;
    split8(v, h, l);
    *reinterpret_cast<short8*>(H + ((size_t)r << 3)) = h;
    *reinterpret_cast<short8*>(L + ((size_t)r << 3)) = l;
}

// ---------------------------------------------------------------------------
// Encoder (R15/16 structure: global_load_lds staging, pre-swizzled source)
// ---------------------------------------------------------------------------
__global__ __launch_bounds__(256, 4) void enc_lds_kernel(
    const float* __restrict__ des, const float* __restrict__ tweet,
    const short* __restrict__ wdes_hi, const short* __restrict__ wdes_lo,
    const short* __restrict__ wtw_hi, const short* __restrict__ wtw_lo,
    const float* __restrict__ bd, const float* __restrict__ bt,
    float* __restrict__ x0, int N)
{
    __shared__ char lds[2][16384];
    const int mat = blockIdx.y;
    const float* __restrict__ X = mat ? tweet : des;
    const short* __restrict__ WH = mat ? wtw_hi : wdes_hi;
    const short* __restrict__ WL = mat ? wtw_lo : wdes_lo;
    const float* __restrict__ B = mat ? bt : bd;

    const int t = threadIdx.x;
    const int lane = t & 63;
    const int wv = t >> 6;
    const int n0 = blockIdx.x * 64;

    const int srow_in_seg = lane >> 4;
    const int sunit = lane & 15;

    f32x4 acc0 = {}, acc1 = {};

    auto stage = [&](int b, int p) {
        #pragma unroll
        for (int i = 0; i < 4; ++i) {
            int seg = wv * 4 + i;
            int row = seg * 4 + srow_in_seg;
            int qsrc = sunit ^ (row & 7);
            int rowg = n0 + row;
            if (rowg >= N) rowg = N - 1;
            const char* g = (const char*)X + (size_t)rowg * 3072 + (size_t)p * 256 + qsrc * 16;
            __builtin_amdgcn_global_load_lds((const unsigned*)g,
                                             (unsigned*)&lds[b][seg * 1024], 16, 0, 0);
        }
    };

    const int frow = wv * 16 + (lane & 15);
    const int kq = (lane >> 4) * 2;

    stage(0, 0);
    for (int p = 0; p < 12; ++p) {
        const int b = p & 1;
        if (p < 11) stage(b ^ 1, p + 1);
        __syncthreads();
        #pragma unroll
        for (int kcl = 0; kcl < 2; ++kcl) {
            int q0 = kcl * 8 + kq;
            float4 u0 = *reinterpret_cast<const float4*>(
                &lds[b][frow * 256 + ((q0 ^ (frow & 7)) << 4)]);
            float4 u1 = *reinterpret_cast<const float4*>(
                &lds[b][frow * 256 + (((q0 + 1) ^ (frow & 7)) << 4)]);
            float av[8] = {u0.x, u0.y, u0.z, u0.w, u1.x, u1.y, u1.z, u1.w};
            short8 ah, al;
            split8(av, ah, al);
            int kc = p * 2 + kcl;
            short8 wh0 = frag_ld(WH, kc * 2 + 0, lane);
            short8 wl0 = frag_ld(WL, kc * 2 + 0, lane);
            short8 wh1 = frag_ld(WH, kc * 2 + 1, lane);
            short8 wl1 = frag_ld(WL, kc * 2 + 1, lane);
            acc0 = __builtin_amdgcn_mfma_f32_16x16x32_bf16(ah, wh0, acc0, 0, 0, 0);
            acc1 = __builtin_amdgcn_mfma_f32_16x16x32_bf16(ah, wh1, acc1, 0, 0, 0);
            acc0 = __builtin_amdgcn_mfma_f32_16x16x32_bf16(ah, wl0, acc0, 0, 0, 0);
            acc1 = __builtin_amdgcn_mfma_f32_16x16x32_bf16(ah, wl1, acc1, 0, 0, 0);
            acc0 = __builtin_amdgcn_mfma_f32_16x16x32_bf16(al, wh0, acc0, 0, 0, 0);
            acc1 = __builtin_amdgcn_mfma_f32_16x16x32_bf16(al, wh1, acc1, 0, 0, 0);
        }
        __syncthreads();
    }

    const int cl = lane & 15;
    float b0 = B[cl], b1 = B[16 + cl];
    const int nodeb = n0 + wv * 16 + (lane >> 4) * 4;
    #pragma unroll
    for (int r = 0; r < 4; ++r) {
        int node = nodeb + r;
        if (node < N) {
            float v0 = acc0[r] + b0; v0 = v0 > 0.f ? v0 : 0.01f * v0;
            float v1 = acc1[r] + b1; v1 = v1 > 0.f ? v1 : 0.01f * v1;
            x0[(size_t)node * HID + mat * 32 + cl] = v0;
            x0[(size_t)node * HID + mat * 32 + 16 + cl] = v1;
        }
    }
}

// x0[:,64:96] = lrelu(num @ W_num + b), x0[:,96:128] = lrelu(cat @ W_cat + b)
__global__ void enc_nc_kernel(const float* __restrict__ num, const float* __restrict__ cat,
                              const float* __restrict__ Wn, const float* __restrict__ bn,
                              const float* __restrict__ Wc, const float* __restrict__ bc,
                              float* __restrict__ x0, int N)
{
    int tid = blockIdx.x * blockDim.x + threadIdx.x;
    int col = tid & 63;
    int node = tid >> 6;
    if (node >= N) return;
    float a;
    if (col < 32) {
        const float* r = num + (size_t)node * 5;
        float acc = bn[col];
        #pragma unroll
        for (int k = 0; k < 5; ++k) acc = fmaf(r[k], Wn[k * 32 + col], acc);
        a = acc;
    } else {
        int c = col & 31;
        a = fmaf(cat[node], Wc[c], bc[c]);
    }
    a = a > 0.f ? a : 0.01f * a;
    x0[(size_t)node * HID + 64 + col] = a;
}

// ---------------------------------------------------------------------------
// Partition: bucket edges (gcur = per-bucket COUNTS, memset 0; pos = b*CAP+off)
// ---------------------------------------------------------------------------
__global__ void partition_kernel(const int* __restrict__ src, const int* __restrict__ dst,
                                 int* __restrict__ gcur, int2* __restrict__ pairs,
                                 int E, int CAP)
{
    __shared__ int sS[1024], sD[1024];
    __shared__ int bcnt[64], boff[64];
    int nch = (E + 1023) >> 10;
    for (int ch = blockIdx.x; ch < nch; ch += gridDim.x) {
        int base = ch << 10;
        int cnt = E - base; if (cnt > 1024) cnt = 1024;
        for (int i = threadIdx.x; i < cnt; i += 256) { sS[i] = src[base + i]; sD[i] = dst[base + i]; }
        if (threadIdx.x < 64) bcnt[threadIdx.x] = 0;
        __syncthreads();
        for (int i = threadIdx.x; i < cnt; i += 256) atomicAdd(&bcnt[sD[i] >> BSHIFT], 1);
        __syncthreads();
        if (threadIdx.x < 64 && bcnt[threadIdx.x] > 0)
            boff[threadIdx.x] = atomicAdd(&gcur[threadIdx.x], bcnt[threadIdx.x]);
        __syncthreads();
        if (threadIdx.x < 64) bcnt[threadIdx.x] = 0;
        __syncthreads();
        for (int i = threadIdx.x; i < cnt; i += 256) {
            int d = sD[i];
            int b = d >> BSHIFT;
            int r = atomicAdd(&bcnt[b], 1);
            int pos = b * CAP + boff[b] + r;
            pairs[pos] = make_int2(sS[i], d);
        }
        __syncthreads();
    }
}

// histB: (NBUCK, 4) — LDS histogram of one bucket quarter -> atomicAdd to cnt
__global__ void hist_bucket_kernel(const int2* __restrict__ pairs, const int* __restrict__ gcur,
                                   int* __restrict__ cnt, int CAP, int N)
{
    __shared__ int lc[2048];
    int b = blockIdx.x;
    int q = blockIdx.y;
    int beg = b * CAP;
    int size = gcur[b];
    for (int i = threadIdx.x; i < 2048; i += 256) lc[i] = 0;
    __syncthreads();
    int s0 = beg + (int)(((long long)size * q) >> 2);
    int s1 = beg + (int)(((long long)size * (q + 1)) >> 2);
    for (int i = s0 + threadIdx.x; i < s1; i += 256)
        atomicAdd(&lc[pairs[i].y & 2047], 1);
    __syncthreads();
    int nodeb = b << BSHIFT;
    for (int i = threadIdx.x; i < 2048; i += 256) {
        if (lc[i] && nodeb + i < N) atomicAdd(&cnt[nodeb + i], lc[i]);
    }
}

__global__ void scan_block_kernel(const int* __restrict__ cnt, int* __restrict__ excl_out,
                                  int* __restrict__ part, int N)
{
    __shared__ int s[256];
    int t = threadIdx.x;
    int i = blockIdx.x * 256 + t;
    int v = (i < N) ? cnt[i] : 0;
    s[t] = v;
    __syncthreads();
    #pragma unroll
    for (int off = 1; off < 256; off <<= 1) {
        int x = (t >= off) ? s[t - off] : 0;
        __syncthreads();
        s[t] += x;
        __syncthreads();
    }
    int incl = s[t];
    if (i < N) excl_out[i] = incl - v;
    if (t == 255) part[blockIdx.x] = incl;
}

__global__ void scan_part_kernel(int* __restrict__ part, int B)
{
    __shared__ int s[512];
    int t = threadIdx.x;
    int v = (t < B) ? part[t] : 0;
    s[t] = v;
    __syncthreads();
    #pragma unroll
    for (int off = 1; off < 512; off <<= 1) {
        int x = (t >= off) ? s[t - off] : 0;
        __syncthreads();
        s[t] += x;
        __syncthreads();
    }
    int incl = s[t];
    if (t < B) part[t] = incl - v;
    if (t == B - 1) part[B] = incl;
}

__global__ void scan_final_kernel(int* __restrict__ row_ptr, const int* __restrict__ part,
                                  int* __restrict__ cursor, const int* __restrict__ cnt,
                                  float* __restrict__ dinv, int N, int B)
{
    int i = blockIdx.x * blockDim.x + threadIdx.x;
    if (i < N) {
        int rp = row_ptr[i] + part[i >> 8];
        row_ptr[i] = rp;
        cursor[i] = rp;
        dinv[i] = rsqrtf((float)(cnt[i] + 1));
    } else if (i == N) {
        row_ptr[N] = part[B];
    }
}

// scatterB: 16 sub-blocks per bucket
__global__ void scatterB_kernel(const int2* __restrict__ pairs, const int* __restrict__ gcur,
                                int* __restrict__ cursor, int* __restrict__ col_idx, int CAP)
{
    int b = blockIdx.x >> 4;
    int q = blockIdx.x & 15;
    int beg = b * CAP;
    int size = gcur[b];
    int qs = beg + (int)(((long long)size * q) >> 4);
    int qe = beg + (int)(((long long)size * (q + 1)) >> 4);
    for (int i = qs + threadIdx.x; i < qe; i += 256) {
        int2 p = pairs[i];
        int pos = atomicAdd(&cursor[p.y], 1);
        col_idx[pos] = p.x;
    }
}

// ---------------------------------------------------------------------------
// Fused x1+g1 (R14 structure)
// ---------------------------------------------------------------------------
__global__ __launch_bounds__(512, 4) void fused_x1g1_kernel(
    const float* __restrict__ in,
    const short* __restrict__ WH1, const short* __restrict__ WL1, const float* __restrict__ b1,
    const short* __restrict__ WH2, const short* __restrict__ WL2,
    const float* __restrict__ dinv, unsigned* __restrict__ outp, int N)
{
    __shared__ char lds[8 * 4096];
    const int t = threadIdx.x;
    const int lane = t & 63;
    const int wv = t >> 6;
    const int n0 = blockIdx.x * 128;
    const int arow = n0 + wv * 16 + (lane & 15);
    const bool valid = arow < N;
    const int cl = lane & 15;
    const int rq = lane >> 4;

    f32x4 acc[8] = {};
    #pragma unroll
    for (int kc = 0; kc < 4; ++kc) {
        float av[8] = {};
        if (valid) {
            const float* ap = in + (size_t)arow * HID + rq * 8;
            float4 u0 = *reinterpret_cast<const float4*>(ap + kc * 32);
            float4 u1 = *reinterpret_cast<const float4*>(ap + kc * 32 + 4);
            av[0] = u0.x; av[1] = u0.y; av[2] = u0.z; av[3] = u0.w;
            av[4] = u1.x; av[5] = u1.y; av[6] = u1.z; av[7] = u1.w;
        }
        short8 ah, al;
        split8(av, ah, al);
        #pragma unroll
        for (int nt = 0; nt < 8; ++nt) {
            short8 wh = frag_ld(WH1, kc * 8 + nt, lane);
            short8 wl = frag_ld(WL1, kc * 8 + nt, lane);
            acc[nt] = __builtin_amdgcn_mfma_f32_16x16x32_bf16(ah, wh, acc[nt], 0, 0, 0);
            acc[nt] = __builtin_amdgcn_mfma_f32_16x16x32_bf16(ah, wl, acc[nt], 0, 0, 0);
            acc[nt] = __builtin_amdgcn_mfma_f32_16x16x32_bf16(al, wh, acc[nt], 0, 0, 0);
        }
    }

    char* my = lds + wv * 4096;
    #pragma unroll
    for (int nt = 0; nt < 8; ++nt) {
        float bb = b1[nt * 16 + cl];
        #pragma unroll
        for (int r = 0; r < 4; ++r) {
            float v = acc[nt][r] + bb;
            v = v > 0.f ? v : 0.01f * v;
            float pv = __shfl_xor(v, 1);
            if ((lane & 1) == 0) {
                unsigned uv = pack_bf16(v, pv);
                int row = rq * 4 + r;
                int col = nt * 16 + cl;
                int unit = col >> 3;
                int off = ((col & 7) >> 1) << 2;
                *reinterpret_cast<unsigned*>(my + lds_addr(row, unit) + off) = uv;
            }
        }
    }
    __syncthreads();

    f32x4 acc2[8] = {};
    #pragma unroll
    for (int kc = 0; kc < 4; ++kc) {
        short8 ah = *reinterpret_cast<short8*>(my + lds_addr(cl, kc * 4 + rq));
        #pragma unroll
        for (int nt = 0; nt < 8; ++nt) {
            short8 wh = frag_ld(WH2, kc * 8 + nt, lane);
            short8 wl = frag_ld(WL2, kc * 8 + nt, lane);
            acc2[nt] = __builtin_amdgcn_mfma_f32_16x16x32_bf16(ah, wh, acc2[nt], 0, 0, 0);
            acc2[nt] = __builtin_amdgcn_mfma_f32_16x16x32_bf16(ah, wl, acc2[nt], 0, 0, 0);
        }
    }

    const int nodeb = n0 + wv * 16 + rq * 4;
    float di[4];
    #pragma unroll
    for (int r = 0; r < 4; ++r)
        di[r] = (nodeb + r < N) ? dinv[nodeb + r] : 0.f;
    #pragma unroll
    for (int nt = 0; nt < 8; ++nt) {
        int c = nt * 16 + cl;
        #pragma unroll
        for (int r = 0; r < 4; ++r) {
            float v = acc2[nt][r] * di[r];
            float pv = __shfl_xor(v, 1);
            int node = nodeb + r;
            if ((lane & 1) == 0 && node < N) {
                unsigned u = pack_bf16(v, pv);
                outp[(size_t)node * (HID / 2) + (c >> 1)] = u;
            }
        }
    }
}

// ---------------------------------------------------------------------------
// Fused conv + gemm (R14 structure)
// ---------------------------------------------------------------------------
template<bool OUT2>
__global__ __launch_bounds__(512, 4) void fused_convgemm_kernel(
    const unsigned* __restrict__ hs, const int* __restrict__ row_ptr,
    const int* __restrict__ col_idx, const float* __restrict__ dinv,
    const float* __restrict__ bconv,
    const short* __restrict__ WH, const short* __restrict__ WL,
    const float* __restrict__ bgem, const float* __restrict__ W2,
    const float* __restrict__ b2, void* __restrict__ outp, int N)
{
    __shared__ char lds[32 * 256];
    __shared__ float red[2][16][4][2];
    const int t = threadIdx.x;
    const int lane = t & 63;
    const int wv = t >> 6;
    const int n0 = blockIdx.x * 32;

    {
        int nl = t >> 4;
        int f = t & 15;
        int node = n0 + nl;
        float a[8] = {};
        if (node < N) {
            const uint4* base = reinterpret_cast<const uint4*>(hs);
            uint4 v0 = base[(size_t)node * 16 + f];
            a[0] = bf16_lo(v0.x); a[1] = bf16_hi(v0.x);
            a[2] = bf16_lo(v0.y); a[3] = bf16_hi(v0.y);
            a[4] = bf16_lo(v0.z); a[5] = bf16_hi(v0.z);
            a[6] = bf16_lo(v0.w); a[7] = bf16_hi(v0.w);
            int e = row_ptr[node], end = row_ptr[node + 1];
            int idx = (e + f < end) ? col_idx[e + f] : 0;
            while (e < end) {
                int m = end - e;
                int curidx = idx;
                if (e + 16 + f < end) idx = col_idx[e + 16 + f];
                if (m >= 16) {
                    #pragma unroll 16
                    for (int j = 0; j < 16; ++j) {
                        int s = __shfl(curidx, j, 16);
                        uint4 v = base[(size_t)s * 16 + f];
                        a[0] += bf16_lo(v.x); a[1] += bf16_hi(v.x);
                        a[2] += bf16_lo(v.y); a[3] += bf16_hi(v.y);
                        a[4] += bf16_lo(v.z); a[5] += bf16_hi(v.z);
                        a[6] += bf16_lo(v.w); a[7] += bf16_hi(v.w);
                    }
                    e += 16;
                } else {
                    for (int j = 0; j < m; ++j) {
                        int s = __shfl(curidx, j, 16);
                        uint4 v = base[(size_t)s * 16 + f];
                        a[0] += bf16_lo(v.x); a[1] += bf16_hi(v.x);
                        a[2] += bf16_lo(v.y); a[3] += bf16_hi(v.y);
                        a[4] += bf16_lo(v.z); a[5] += bf16_hi(v.z);
                        a[6] += bf16_lo(v.w); a[7] += bf16_hi(v.w);
                    }
                    e = end;
                }
            }
            float di = dinv[node];
            const float* bb = bconv + f * 8;
            #pragma unroll
            for (int j = 0; j < 8; ++j) a[j] = fmaf(di, a[j], bb[j]);
        }
        uint4 o;
        o.x = pack_bf16(a[0], a[1]);
        o.y = pack_bf16(a[2], a[3]);
        o.z = pack_bf16(a[4], a[5]);
        o.w = pack_bf16(a[6], a[7]);
        *reinterpret_cast<uint4*>(lds + lds_addr(nl, f)) = o;
    }
    __syncthreads();

    const int cl = lane & 15;
    const int rq = lane >> 4;
    const int mt = wv >> 2;
    const int ntp = wv & 3;
    f32x4 acc[2] = {};
    #pragma unroll
    for (int kc = 0; kc < 4; ++kc) {
        short8 ah = *reinterpret_cast<short8*>(lds + lds_addr(mt * 16 + cl, kc * 4 + rq));
        #pragma unroll
        for (int i = 0; i < 2; ++i) {
            int nt = ntp * 2 + i;
            short8 wh = frag_ld(WH, kc * 8 + nt, lane);
            short8 wl = frag_ld(WL, kc * 8 + nt, lane);
            acc[i] = __builtin_amdgcn_mfma_f32_16x16x32_bf16(ah, wh, acc[i], 0, 0, 0);
            acc[i] = __builtin_amdgcn_mfma_f32_16x16x32_bf16(ah, wl, acc[i], 0, 0, 0);
        }
    }

    const int nodeb = n0 + mt * 16 + rq * 4;

    if (!OUT2) {
        float di[4];
        #pragma unroll
        for (int r = 0; r < 4; ++r)
            di[r] = (nodeb + r < N) ? dinv[nodeb + r] : 0.f;
        #pragma unroll
        for (int i = 0; i < 2; ++i) {
            int c = (ntp * 2 + i) * 16 + cl;
            #pragma unroll
            for (int r = 0; r < 4; ++r) {
                float v = acc[i][r] * di[r];
                float pv = __shfl_xor(v, 1);
                int node = nodeb + r;
                if ((lane & 1) == 0 && node < N) {
                    unsigned u = pack_bf16(v, pv);
                    reinterpret_cast<unsigned*>(outp)[(size_t)node * (HID / 2) + (c >> 1)] = u;
                }
            }
        }
    } else {
        float p0[4] = {}, p1[4] = {};
        #pragma unroll
        for (int i = 0; i < 2; ++i) {
            int c = (ntp * 2 + i) * 16 + cl;
            float bb = bgem[c];
            float w20 = W2[c * 2 + 0], w21 = W2[c * 2 + 1];
            #pragma unroll
            for (int r = 0; r < 4; ++r) {
                float v = acc[i][r] + bb;
                v = v > 0.f ? v : 0.01f * v;
                p0[r] = fmaf(v, w20, p0[r]);
                p1[r] = fmaf(v, w21, p1[r]);
            }
        }
        #pragma unroll
        for (int r = 0; r < 4; ++r) {
            #pragma unroll
            for (int m = 1; m < 16; m <<= 1) {
                p0[r] += __shfl_xor(p0[r], m);
                p1[r] += __shfl_xor(p1[r], m);
            }
        }
        if (cl == 0) {
            #pragma unroll
            for (int r = 0; r < 4; ++r) {
                red[mt][rq * 4 + r][ntp][0] = p0[r];
                red[mt][rq * 4 + r][ntp][1] = p1[r];
            }
        }
        __syncthreads();
        if (t < 64) {
            int nl2 = t >> 1, comp = t & 1;
            int mtt = nl2 >> 4, rr = nl2 & 15;
            float s = red[mtt][rr][0][comp] + red[mtt][rr][1][comp]
                    + red[mtt][rr][2][comp] + red[mtt][rr][3][comp] + b2[comp];
            int node = n0 + nl2;
            if (node < N)
                reinterpret_cast<float*>(outp)[(size_t)node * 2 + comp] = s;
        }
    }
}

extern "C" void kernel_launch(void* const* d_in, const int* in_sizes, int n_in,
                              void* d_out, int out_size, void* d_ws, size_t ws_size,
                              hipStream_t stream)
{
    const float* des   = (const float*)d_in[0];
    const float* tweet = (const float*)d_in[1];
    const float* num   = (const float*)d_in[2];
    const float* cat   = (const float*)d_in[3];
    const int*   eidx  = (const int*)d_in[4];
    const float* W_des = (const float*)d_in[5];  const float* b_des = (const float*)d_in[6];
    const float* W_tw  = (const float*)d_in[7];  const float* b_tw  = (const float*)d_in[8];
    const float* W_num = (const float*)d_in[9];  const float* b_num = (const float*)d_in[10];
    const float* W_cat = (const float*)d_in[11]; const float* b_cat = (const float*)d_in[12];
    const float* W_in  = (const float*)d_in[13]; const float* b_in  = (const float*)d_in[14];
    const float* W_g1  = (const float*)d_in[15]; const float* b_g1  = (const float*)d_in[16];
    const float* W_g2  = (const float*)d_in[17]; const float* b_g2  = (const float*)d_in[18];
    const float* W_o1  = (const float*)d_in[19]; const float* b_o1  = (const float*)d_in[20];
    const float* W_o2  = (const float*)d_in[21]; const float* b_o2  = (const float*)d_in[22];
    float* out = (float*)d_out;

    const int N = in_sizes[0] / 768;
    const int E = in_sizes[4] / 2;
    const int* src = eidx;
    const int* dst = eidx + E;

    const int NBUCK = (N + 2047) >> BSHIFT;          // <= 64 required
    const int CAP = (E / (NBUCK > 0 ? NBUCK : 1)) + (E / (NBUCK > 0 ? NBUCK : 1)) / 4 + 4096;

    // workspace layout
    char* ws = (char*)d_ws;
    const size_t szF = (size_t)N * HID * sizeof(float);
    float* F0 = (float*)ws;                    ws += szF;
    float* F1 = (float*)ws;                    ws += szF;
    float* F2 = (float*)ws;                    ws += szF;
    int* cnt      = (int*)ws;                  ws += ((size_t)N * 4 + 255) & ~255ULL;
    int* row_ptr  = (int*)ws;                  ws += (((size_t)N + 1) * 4 + 255) & ~255ULL;
    int* cursor   = (int*)ws;                  ws += ((size_t)N * 4 + 255) & ~255ULL;
    int* part     = (int*)ws;                  ws += 4096;
    float* dinv   = (float*)ws;                ws += ((size_t)N * 4 + 255) & ~255ULL;
    int* gcur     = (int*)ws;                  ws += 256;
    const size_t sz768 = 768 * 32 * sizeof(short);
    const size_t sz128 = 128 * 128 * sizeof(short);
    short* wdes_hi = (short*)ws; ws += sz768;  short* wdes_lo = (short*)ws; ws += sz768;
    short* wtw_hi  = (short*)ws; ws += sz768;  short* wtw_lo  = (short*)ws; ws += sz768;
    short* win_hi  = (short*)ws; ws += sz128;  short* win_lo  = (short*)ws; ws += sz128;
    short* wg1_hi  = (short*)ws; ws += sz128;  short* wg1_lo  = (short*)ws; ws += sz128;
    short* wg2_hi  = (short*)ws; ws += sz128;  short* wg2_lo  = (short*)ws; ws += sz128;
    short* wo1_hi  = (short*)ws; ws += sz128;  short* wo1_lo  = (short*)ws; ws += sz128;
    int* col_idx  = (int*)ws;                  ws += ((size_t)E * 4 + 255) & ~255ULL;
    int2* pairs   = (int2*)ws;                 ws += (size_t)NBUCK * CAP * 8;

    const int B = (N + 255) / 256;

    // ---- weight fragment conversion ----
    {
        dim3 grid(12, 6);
        convert_w_kernel<<<grid, 256, 0, stream>>>(
            W_des, W_tw, W_in, W_g1, W_g2, W_o1,
            wdes_hi, wdes_lo, wtw_hi, wtw_lo, win_hi, win_lo,
            wg1_hi, wg1_lo, wg2_hi, wg2_lo, wo1_hi, wo1_lo);
    }

    // ---- CSR build (bucket partition) ----
    hipMemsetAsync(gcur, 0, 256, stream);
    hipMemsetAsync(cnt, 0, (size_t)N * sizeof(int), stream);
    partition_kernel<<<2048, 256, 0, stream>>>(src, dst, gcur, pairs, E, CAP);
    {
        dim3 hg(NBUCK, 4);
        hist_bucket_kernel<<<hg, 256, 0, stream>>>(pairs, gcur, cnt, CAP, N);
    }
    scan_block_kernel<<<B, 256, 0, stream>>>(cnt, row_ptr, part, N);
    scan_part_kernel<<<1, 512, 0, stream>>>(part, B);
    scan_final_kernel<<<(N + 256) / 256 + 1, 256, 0, stream>>>(row_ptr, part, cursor, cnt, dinv, N, B);
    scatterB_kernel<<<NBUCK * 16, 256, 0, stream>>>(pairs, gcur, cursor, col_idx, CAP);

    // ---- encoder -> F0 (f32 x0) ----
    {
        dim3 grid((N + 63) / 64, 2);
        enc_lds_kernel<<<grid, 256, 0, stream>>>(des, tweet, wdes_hi, wdes_lo,
                                                 wtw_hi, wtw_lo, b_des, b_tw, F0, N);
        enc_nc_kernel<<<((size_t)N * 64 + 255) / 256, 256, 0, stream>>>(num, cat, W_num, b_num, W_cat, b_cat, F0, N);
    }

    // ---- fused x1+g1: F0 (f32) -> F2 (hs1 bf16) ----
    fused_x1g1_kernel<<<(N + 127) / 128, 512, 0, stream>>>(
        F0, win_hi, win_lo, b_in, wg1_hi, wg1_lo, dinv, (unsigned*)F2, N);

    // ---- fused conv1+g2: F2 -> F1 (hs2 bf16) ----
    fused_convgemm_kernel<false><<<(N + 31) / 32, 512, 0, stream>>>(
        (const unsigned*)F2, row_ptr, col_idx, dinv, b_g1,
        wg2_hi, wg2_lo, nullptr, nullptr, nullptr, F1, N);

    // ---- fused conv2+o1+out2: F1 -> out ----
    fused_convgemm_kernel<true><<<(N + 31) / 32, 512, 0, stream>>>(
        (const unsigned*)F1, row_ptr, col_idx, dinv, b_g2,
        wo1_hi, wo1_lo, b_o1, W_o2, b_o2, out, N);
}

// Round 19
// 620.523 us; speedup vs baseline: 1.3089x; 1.3089x over previous
//
#include <hip/hip_runtime.h>
#include <hip/hip_bf16.h>
#include <cstdint>

#define HID 128
#define BSHIFT 9    // 512 nodes per bucket
#define BNODES 512

typedef short short8 __attribute__((ext_vector_type(8)));
typedef float f32x4 __attribute__((ext_vector_type(4)));

__device__ __forceinline__ unsigned pack_bf16(float a, float b)
{
    __hip_bfloat16 ha = __float2bfloat16(a);
    __hip_bfloat16 hb = __float2bfloat16(b);
    unsigned short ua = *reinterpret_cast<unsigned short*>(&ha);
    unsigned short ub = *reinterpret_cast<unsigned short*>(&hb);
    return (unsigned)ua | ((unsigned)ub << 16);
}

__device__ __forceinline__ float bf16_lo(unsigned u)
{
    unsigned v = u << 16;
    return *reinterpret_cast<float*>(&v);
}
__device__ __forceinline__ float bf16_hi(unsigned u)
{
    unsigned v = u & 0xffff0000u;
    return *reinterpret_cast<float*>(&v);
}

__device__ __forceinline__ void split8(const float* v, short8& h, short8& l)
{
    #pragma unroll
    for (int j = 0; j < 8; ++j) {
        unsigned bits = __float_as_uint(v[j]);
        h[j] = (short)(bits >> 16);
        unsigned hb = bits & 0xffff0000u;
        float lof = v[j] - __uint_as_float(hb);
        l[j] = (short)(__float_as_uint(lof) >> 16);
    }
}

__device__ __forceinline__ short8 frag_ld(const short* __restrict__ base, int tile, int lane)
{
    return *reinterpret_cast<const short8*>(base + (((size_t)tile * 64 + lane) << 3));
}

__device__ __forceinline__ int lds_addr(int row, int unit)
{
    return row * 256 + ((unit ^ (row & 7)) << 4);
}

// ---------------------------------------------------------------------------
// One-shot weight conversion
// ---------------------------------------------------------------------------
__global__ void convert_w_kernel(
    const float* W0, const float* W1, const float* W2,
    const float* W3, const float* W4, const float* W5,
    short* H0, short* L0, short* H1, short* L1, short* H2, short* L2,
    short* H3, short* L3, short* H4, short* L4, short* H5, short* L5)
{
    int job = blockIdx.y;
    const float* W; short* H; short* L; int K, C;
    switch (job) {
        case 0: W = W0; H = H0; L = L0; K = 768; C = 32;  break;
        case 1: W = W1; H = H1; L = L1; K = 768; C = 32;  break;
        case 2: W = W2; H = H2; L = L2; K = 128; C = 128; break;
        case 3: W = W3; H = H3; L = L3; K = 128; C = 128; break;
        case 4: W = W4; H = H4; L = L4; K = 128; C = 128; break;
        default: W = W5; H = H5; L = L5; K = 128; C = 128; break;
    }
    int NT = C >> 4;
    int rows = (K >> 5) * NT * 64;
    int r = blockIdx.x * blockDim.x + threadIdx.x;
    if (r >= rows) return;
    int lane = r & 63;
    int tile = r >> 6;
    int c = (tile % NT) * 16 + (lane & 15);
    int kbase = (tile / NT) * 32 + ((lane >> 4) & 3) * 8;
    float v[8];
    #pragma unroll
    for (int j = 0; j < 8; ++j) v[j] = W[(size_t)(kbase + j) * C + c];
    short8 h, l;
    split8(v, h, l);
    *reinterpret_cast<short8*>(H + ((size_t)r << 3)) = h;
    *reinterpret_cast<short8*>(L + ((size_t)r << 3)) = l;
}

// ---------------------------------------------------------------------------
// Encoder (R15/16 structure)
// ---------------------------------------------------------------------------
__global__ __launch_bounds__(256, 4) void enc_lds_kernel(
    const float* __restrict__ des, const float* __restrict__ tweet,
    const short* __restrict__ wdes_hi, const short* __restrict__ wdes_lo,
    const short* __restrict__ wtw_hi, const short* __restrict__ wtw_lo,
    const float* __restrict__ bd, const float* __restrict__ bt,
    float* __restrict__ x0, int N)
{
    __shared__ char lds[2][16384];
    const int mat = blockIdx.y;
    const float* __restrict__ X = mat ? tweet : des;
    const short* __restrict__ WH = mat ? wtw_hi : wdes_hi;
    const short* __restrict__ WL = mat ? wtw_lo : wdes_lo;
    const float* __restrict__ B = mat ? bt : bd;

    const int t = threadIdx.x;
    const int lane = t & 63;
    const int wv = t >> 6;
    const int n0 = blockIdx.x * 64;

    const int srow_in_seg = lane >> 4;
    const int sunit = lane & 15;

    f32x4 acc0 = {}, acc1 = {};

    auto stage = [&](int b, int p) {
        #pragma unroll
        for (int i = 0; i < 4; ++i) {
            int seg = wv * 4 + i;
            int row = seg * 4 + srow_in_seg;
            int qsrc = sunit ^ (row & 7);
            int rowg = n0 + row;
            if (rowg >= N) rowg = N - 1;
            const char* g = (const char*)X + (size_t)rowg * 3072 + (size_t)p * 256 + qsrc * 16;
            __builtin_amdgcn_global_load_lds((const unsigned*)g,
                                             (unsigned*)&lds[b][seg * 1024], 16, 0, 0);
        }
    };

    const int frow = wv * 16 + (lane & 15);
    const int kq = (lane >> 4) * 2;

    stage(0, 0);
    for (int p = 0; p < 12; ++p) {
        const int b = p & 1;
        if (p < 11) stage(b ^ 1, p + 1);
        __syncthreads();
        #pragma unroll
        for (int kcl = 0; kcl < 2; ++kcl) {
            int q0 = kcl * 8 + kq;
            float4 u0 = *reinterpret_cast<const float4*>(
                &lds[b][frow * 256 + ((q0 ^ (frow & 7)) << 4)]);
            float4 u1 = *reinterpret_cast<const float4*>(
                &lds[b][frow * 256 + (((q0 + 1) ^ (frow & 7)) << 4)]);
            float av[8] = {u0.x, u0.y, u0.z, u0.w, u1.x, u1.y, u1.z, u1.w};
            short8 ah, al;
            split8(av, ah, al);
            int kc = p * 2 + kcl;
            short8 wh0 = frag_ld(WH, kc * 2 + 0, lane);
            short8 wl0 = frag_ld(WL, kc * 2 + 0, lane);
            short8 wh1 = frag_ld(WH, kc * 2 + 1, lane);
            short8 wl1 = frag_ld(WL, kc * 2 + 1, lane);
            acc0 = __builtin_amdgcn_mfma_f32_16x16x32_bf16(ah, wh0, acc0, 0, 0, 0);
            acc1 = __builtin_amdgcn_mfma_f32_16x16x32_bf16(ah, wh1, acc1, 0, 0, 0);
            acc0 = __builtin_amdgcn_mfma_f32_16x16x32_bf16(ah, wl0, acc0, 0, 0, 0);
            acc1 = __builtin_amdgcn_mfma_f32_16x16x32_bf16(ah, wl1, acc1, 0, 0, 0);
            acc0 = __builtin_amdgcn_mfma_f32_16x16x32_bf16(al, wh0, acc0, 0, 0, 0);
            acc1 = __builtin_amdgcn_mfma_f32_16x16x32_bf16(al, wh1, acc1, 0, 0, 0);
        }
        __syncthreads();
    }

    const int cl = lane & 15;
    float b0 = B[cl], b1 = B[16 + cl];
    const int nodeb = n0 + wv * 16 + (lane >> 4) * 4;
    #pragma unroll
    for (int r = 0; r < 4; ++r) {
        int node = nodeb + r;
        if (node < N) {
            float v0 = acc0[r] + b0; v0 = v0 > 0.f ? v0 : 0.01f * v0;
            float v1 = acc1[r] + b1; v1 = v1 > 0.f ? v1 : 0.01f * v1;
            x0[(size_t)node * HID + mat * 32 + cl] = v0;
            x0[(size_t)node * HID + mat * 32 + 16 + cl] = v1;
        }
    }
}

// x0[:,64:96] = lrelu(num @ W_num + b), x0[:,96:128] = lrelu(cat @ W_cat + b)
__global__ void enc_nc_kernel(const float* __restrict__ num, const float* __restrict__ cat,
                              const float* __restrict__ Wn, const float* __restrict__ bn,
                              const float* __restrict__ Wc, const float* __restrict__ bc,
                              float* __restrict__ x0, int N)
{
    int tid = blockIdx.x * blockDim.x + threadIdx.x;
    int col = tid & 63;
    int node = tid >> 6;
    if (node >= N) return;
    float a;
    if (col < 32) {
        const float* r = num + (size_t)node * 5;
        float acc = bn[col];
        #pragma unroll
        for (int k = 0; k < 5; ++k) acc = fmaf(r[k], Wn[k * 32 + col], acc);
        a = acc;
    } else {
        int c = col & 31;
        a = fmaf(cat[node], Wc[c], bc[c]);
    }
    a = a > 0.f ? a : 0.01f * a;
    x0[(size_t)node * HID + 64 + col] = a;
}

// ---------------------------------------------------------------------------
// Partition: bucket edges into 512-node dst buckets (up to 256 buckets)
// ---------------------------------------------------------------------------
__global__ void partition_kernel(const int* __restrict__ src, const int* __restrict__ dst,
                                 int* __restrict__ gcur, int2* __restrict__ pairs,
                                 int E, int CAP)
{
    __shared__ int sS[1024], sD[1024];
    __shared__ int bcnt[256], boff[256];
    int nch = (E + 1023) >> 10;
    for (int ch = blockIdx.x; ch < nch; ch += gridDim.x) {
        int base = ch << 10;
        int cnt = E - base; if (cnt > 1024) cnt = 1024;
        for (int i = threadIdx.x; i < cnt; i += 256) { sS[i] = src[base + i]; sD[i] = dst[base + i]; }
        bcnt[threadIdx.x] = 0;
        __syncthreads();
        for (int i = threadIdx.x; i < cnt; i += 256) atomicAdd(&bcnt[sD[i] >> BSHIFT], 1);
        __syncthreads();
        if (bcnt[threadIdx.x] > 0)
            boff[threadIdx.x] = atomicAdd(&gcur[threadIdx.x], bcnt[threadIdx.x]);
        __syncthreads();
        bcnt[threadIdx.x] = 0;
        __syncthreads();
        for (int i = threadIdx.x; i < cnt; i += 256) {
            int d = sD[i];
            int b = d >> BSHIFT;
            int r = atomicAdd(&bcnt[b], 1);
            int pos = b * CAP + boff[b] + r;
            pairs[pos] = make_int2(sS[i], d);
        }
        __syncthreads();
    }
}

// histB: (NBUCK, 2) — LDS histogram of one bucket half -> atomicAdd to cnt
__global__ void hist_bucket_kernel(const int2* __restrict__ pairs, const int* __restrict__ gcur,
                                   int* __restrict__ cnt, int CAP, int N)
{
    __shared__ int lc[BNODES];
    int b = blockIdx.x;
    int q = blockIdx.y;
    int beg = b * CAP;
    int size = gcur[b];
    for (int i = threadIdx.x; i < BNODES; i += 256) lc[i] = 0;
    __syncthreads();
    int s0 = beg + (int)(((long long)size * q) >> 1);
    int s1 = beg + (int)(((long long)size * (q + 1)) >> 1);
    for (int i = s0 + threadIdx.x; i < s1; i += 256)
        atomicAdd(&lc[pairs[i].y & (BNODES - 1)], 1);
    __syncthreads();
    int nodeb = b << BSHIFT;
    for (int i = threadIdx.x; i < BNODES; i += 256) {
        if (lc[i] && nodeb + i < N) atomicAdd(&cnt[nodeb + i], lc[i]);
    }
}

__global__ void scan_block_kernel(const int* __restrict__ cnt, int* __restrict__ excl_out,
                                  int* __restrict__ part, int N)
{
    __shared__ int s[256];
    int t = threadIdx.x;
    int i = blockIdx.x * 256 + t;
    int v = (i < N) ? cnt[i] : 0;
    s[t] = v;
    __syncthreads();
    #pragma unroll
    for (int off = 1; off < 256; off <<= 1) {
        int x = (t >= off) ? s[t - off] : 0;
        __syncthreads();
        s[t] += x;
        __syncthreads();
    }
    int incl = s[t];
    if (i < N) excl_out[i] = incl - v;
    if (t == 255) part[blockIdx.x] = incl;
}

__global__ void scan_part_kernel(int* __restrict__ part, int B)
{
    __shared__ int s[512];
    int t = threadIdx.x;
    int v = (t < B) ? part[t] : 0;
    s[t] = v;
    __syncthreads();
    #pragma unroll
    for (int off = 1; off < 512; off <<= 1) {
        int x = (t >= off) ? s[t - off] : 0;
        __syncthreads();
        s[t] += x;
        __syncthreads();
    }
    int incl = s[t];
    if (t < B) part[t] = incl - v;
    if (t == B - 1) part[B] = incl;
}

__global__ void scan_final_kernel(int* __restrict__ row_ptr, const int* __restrict__ part,
                                  const int* __restrict__ cnt,
                                  float* __restrict__ dinv, int N, int B)
{
    int i = blockIdx.x * blockDim.x + threadIdx.x;
    if (i < N) {
        int rp = row_ptr[i] + part[i >> 8];
        row_ptr[i] = rp;
        dinv[i] = rsqrtf((float)(cnt[i] + 1));
    } else if (i == N) {
        row_ptr[N] = part[B];
    }
}

// scatter: ONE block per bucket; cursor lives in LDS (no global atomic churn)
__global__ __launch_bounds__(512) void scatter_lds_kernel(
    const int2* __restrict__ pairs, const int* __restrict__ gcur,
    const int* __restrict__ row_ptr, int* __restrict__ col_idx, int CAP, int N)
{
    __shared__ int lcur[BNODES];
    int b = blockIdx.x;
    int nodeb = b << BSHIFT;
    for (int i = threadIdx.x; i < BNODES; i += 512)
        lcur[i] = (nodeb + i < N) ? row_ptr[nodeb + i] : 0;
    __syncthreads();
    int beg = b * CAP;
    int endp = beg + gcur[b];
    for (int i = beg + threadIdx.x; i < endp; i += 512) {
        int2 p = pairs[i];
        int pos = atomicAdd(&lcur[p.y & (BNODES - 1)], 1);
        col_idx[pos] = p.x;
    }
}

// ---------------------------------------------------------------------------
// Fused x1+g1 (R14 structure)
// ---------------------------------------------------------------------------
__global__ __launch_bounds__(512, 4) void fused_x1g1_kernel(
    const float* __restrict__ in,
    const short* __restrict__ WH1, const short* __restrict__ WL1, const float* __restrict__ b1,
    const short* __restrict__ WH2, const short* __restrict__ WL2,
    const float* __restrict__ dinv, unsigned* __restrict__ outp, int N)
{
    __shared__ char lds[8 * 4096];
    const int t = threadIdx.x;
    const int lane = t & 63;
    const int wv = t >> 6;
    const int n0 = blockIdx.x * 128;
    const int arow = n0 + wv * 16 + (lane & 15);
    const bool valid = arow < N;
    const int cl = lane & 15;
    const int rq = lane >> 4;

    f32x4 acc[8] = {};
    #pragma unroll
    for (int kc = 0; kc < 4; ++kc) {
        float av[8] = {};
        if (valid) {
            const float* ap = in + (size_t)arow * HID + rq * 8;
            float4 u0 = *reinterpret_cast<const float4*>(ap + kc * 32);
            float4 u1 = *reinterpret_cast<const float4*>(ap + kc * 32 + 4);
            av[0] = u0.x; av[1] = u0.y; av[2] = u0.z; av[3] = u0.w;
            av[4] = u1.x; av[5] = u1.y; av[6] = u1.z; av[7] = u1.w;
        }
        short8 ah, al;
        split8(av, ah, al);
        #pragma unroll
        for (int nt = 0; nt < 8; ++nt) {
            short8 wh = frag_ld(WH1, kc * 8 + nt, lane);
            short8 wl = frag_ld(WL1, kc * 8 + nt, lane);
            acc[nt] = __builtin_amdgcn_mfma_f32_16x16x32_bf16(ah, wh, acc[nt], 0, 0, 0);
            acc[nt] = __builtin_amdgcn_mfma_f32_16x16x32_bf16(ah, wl, acc[nt], 0, 0, 0);
            acc[nt] = __builtin_amdgcn_mfma_f32_16x16x32_bf16(al, wh, acc[nt], 0, 0, 0);
        }
    }

    char* my = lds + wv * 4096;
    #pragma unroll
    for (int nt = 0; nt < 8; ++nt) {
        float bb = b1[nt * 16 + cl];
        #pragma unroll
        for (int r = 0; r < 4; ++r) {
            float v = acc[nt][r] + bb;
            v = v > 0.f ? v : 0.01f * v;
            float pv = __shfl_xor(v, 1);
            if ((lane & 1) == 0) {
                unsigned uv = pack_bf16(v, pv);
                int row = rq * 4 + r;
                int col = nt * 16 + cl;
                int unit = col >> 3;
                int off = ((col & 7) >> 1) << 2;
                *reinterpret_cast<unsigned*>(my + lds_addr(row, unit) + off) = uv;
            }
        }
    }
    __syncthreads();

    f32x4 acc2[8] = {};
    #pragma unroll
    for (int kc = 0; kc < 4; ++kc) {
        short8 ah = *reinterpret_cast<short8*>(my + lds_addr(cl, kc * 4 + rq));
        #pragma unroll
        for (int nt = 0; nt < 8; ++nt) {
            short8 wh = frag_ld(WH2, kc * 8 + nt, lane);
            short8 wl = frag_ld(WL2, kc * 8 + nt, lane);
            acc2[nt] = __builtin_amdgcn_mfma_f32_16x16x32_bf16(ah, wh, acc2[nt], 0, 0, 0);
            acc2[nt] = __builtin_amdgcn_mfma_f32_16x16x32_bf16(ah, wl, acc2[nt], 0, 0, 0);
        }
    }

    const int nodeb = n0 + wv * 16 + rq * 4;
    float di[4];
    #pragma unroll
    for (int r = 0; r < 4; ++r)
        di[r] = (nodeb + r < N) ? dinv[nodeb + r] : 0.f;
    #pragma unroll
    for (int nt = 0; nt < 8; ++nt) {
        int c = nt * 16 + cl;
        #pragma unroll
        for (int r = 0; r < 4; ++r) {
            float v = acc2[nt][r] * di[r];
            float pv = __shfl_xor(v, 1);
            int node = nodeb + r;
            if ((lane & 1) == 0 && node < N) {
                unsigned u = pack_bf16(v, pv);
                outp[(size_t)node * (HID / 2) + (c >> 1)] = u;
            }
        }
    }
}

// ---------------------------------------------------------------------------
// Fused conv + gemm (R14 structure)
// ---------------------------------------------------------------------------
template<bool OUT2>
__global__ __launch_bounds__(512, 4) void fused_convgemm_kernel(
    const unsigned* __restrict__ hs, const int* __restrict__ row_ptr,
    const int* __restrict__ col_idx, const float* __restrict__ dinv,
    const float* __restrict__ bconv,
    const short* __restrict__ WH, const short* __restrict__ WL,
    const float* __restrict__ bgem, const float* __restrict__ W2,
    const float* __restrict__ b2, void* __restrict__ outp, int N)
{
    __shared__ char lds[32 * 256];
    __shared__ float red[2][16][4][2];
    const int t = threadIdx.x;
    const int lane = t & 63;
    const int wv = t >> 6;
    const int n0 = blockIdx.x * 32;

    {
        int nl = t >> 4;
        int f = t & 15;
        int node = n0 + nl;
        float a[8] = {};
        if (node < N) {
            const uint4* base = reinterpret_cast<const uint4*>(hs);
            uint4 v0 = base[(size_t)node * 16 + f];
            a[0] = bf16_lo(v0.x); a[1] = bf16_hi(v0.x);
            a[2] = bf16_lo(v0.y); a[3] = bf16_hi(v0.y);
            a[4] = bf16_lo(v0.z); a[5] = bf16_hi(v0.z);
            a[6] = bf16_lo(v0.w); a[7] = bf16_hi(v0.w);
            int e = row_ptr[node], end = row_ptr[node + 1];
            int idx = (e + f < end) ? col_idx[e + f] : 0;
            while (e < end) {
                int m = end - e;
                int curidx = idx;
                if (e + 16 + f < end) idx = col_idx[e + 16 + f];
                if (m >= 16) {
                    #pragma unroll 16
                    for (int j = 0; j < 16; ++j) {
                        int s = __shfl(curidx, j, 16);
                        uint4 v = base[(size_t)s * 16 + f];
                        a[0] += bf16_lo(v.x); a[1] += bf16_hi(v.x);
                        a[2] += bf16_lo(v.y); a[3] += bf16_hi(v.y);
                        a[4] += bf16_lo(v.z); a[5] += bf16_hi(v.z);
                        a[6] += bf16_lo(v.w); a[7] += bf16_hi(v.w);
                    }
                    e += 16;
                } else {
                    for (int j = 0; j < m; ++j) {
                        int s = __shfl(curidx, j, 16);
                        uint4 v = base[(size_t)s * 16 + f];
                        a[0] += bf16_lo(v.x); a[1] += bf16_hi(v.x);
                        a[2] += bf16_lo(v.y); a[3] += bf16_hi(v.y);
                        a[4] += bf16_lo(v.z); a[5] += bf16_hi(v.z);
                        a[6] += bf16_lo(v.w); a[7] += bf16_hi(v.w);
                    }
                    e = end;
                }
            }
            float di = dinv[node];
            const float* bb = bconv + f * 8;
            #pragma unroll
            for (int j = 0; j < 8; ++j) a[j] = fmaf(di, a[j], bb[j]);
        }
        uint4 o;
        o.x = pack_bf16(a[0], a[1]);
        o.y = pack_bf16(a[2], a[3]);
        o.z = pack_bf16(a[4], a[5]);
        o.w = pack_bf16(a[6], a[7]);
        *reinterpret_cast<uint4*>(lds + lds_addr(nl, f)) = o;
    }
    __syncthreads();

    const int cl = lane & 15;
    const int rq = lane >> 4;
    const int mt = wv >> 2;
    const int ntp = wv & 3;
    f32x4 acc[2] = {};
    #pragma unroll
    for (int kc = 0; kc < 4; ++kc) {
        short8 ah = *reinterpret_cast<short8*>(lds + lds_addr(mt * 16 + cl, kc * 4 + rq));
        #pragma unroll
        for (int i = 0; i < 2; ++i) {
            int nt = ntp * 2 + i;
            short8 wh = frag_ld(WH, kc * 8 + nt, lane);
            short8 wl = frag_ld(WL, kc * 8 + nt, lane);
            acc[i] = __builtin_amdgcn_mfma_f32_16x16x32_bf16(ah, wh, acc[i], 0, 0, 0);
            acc[i] = __builtin_amdgcn_mfma_f32_16x16x32_bf16(ah, wl, acc[i], 0, 0, 0);
        }
    }

    const int nodeb = n0 + mt * 16 + rq * 4;

    if (!OUT2) {
        float di[4];
        #pragma unroll
        for (int r = 0; r < 4; ++r)
            di[r] = (nodeb + r < N) ? dinv[nodeb + r] : 0.f;
        #pragma unroll
        for (int i = 0; i < 2; ++i) {
            int c = (ntp * 2 + i) * 16 + cl;
            #pragma unroll
            for (int r = 0; r < 4; ++r) {
                float v = acc[i][r] * di[r];
                float pv = __shfl_xor(v, 1);
                int node = nodeb + r;
                if ((lane & 1) == 0 && node < N) {
                    unsigned u = pack_bf16(v, pv);
                    reinterpret_cast<unsigned*>(outp)[(size_t)node * (HID / 2) + (c >> 1)] = u;
                }
            }
        }
    } else {
        float p0[4] = {}, p1[4] = {};
        #pragma unroll
        for (int i = 0; i < 2; ++i) {
            int c = (ntp * 2 + i) * 16 + cl;
            float bb = bgem[c];
            float w20 = W2[c * 2 + 0], w21 = W2[c * 2 + 1];
            #pragma unroll
            for (int r = 0; r < 4; ++r) {
                float v = acc[i][r] + bb;
                v = v > 0.f ? v : 0.01f * v;
                p0[r] = fmaf(v, w20, p0[r]);
                p1[r] = fmaf(v, w21, p1[r]);
            }
        }
        #pragma unroll
        for (int r = 0; r < 4; ++r) {
            #pragma unroll
            for (int m = 1; m < 16; m <<= 1) {
                p0[r] += __shfl_xor(p0[r], m);
                p1[r] += __shfl_xor(p1[r], m);
            }
        }
        if (cl == 0) {
            #pragma unroll
            for (int r = 0; r < 4; ++r) {
                red[mt][rq * 4 + r][ntp][0] = p0[r];
                red[mt][rq * 4 + r][ntp][1] = p1[r];
            }
        }
        __syncthreads();
        if (t < 64) {
            int nl2 = t >> 1, comp = t & 1;
            int mtt = nl2 >> 4, rr = nl2 & 15;
            float s = red[mtt][rr][0][comp] + red[mtt][rr][1][comp]
                    + red[mtt][rr][2][comp] + red[mtt][rr][3][comp] + b2[comp];
            int node = n0 + nl2;
            if (node < N)
                reinterpret_cast<float*>(outp)[(size_t)node * 2 + comp] = s;
        }
    }
}

extern "C" void kernel_launch(void* const* d_in, const int* in_sizes, int n_in,
                              void* d_out, int out_size, void* d_ws, size_t ws_size,
                              hipStream_t stream)
{
    const float* des   = (const float*)d_in[0];
    const float* tweet = (const float*)d_in[1];
    const float* num   = (const float*)d_in[2];
    const float* cat   = (const float*)d_in[3];
    const int*   eidx  = (const int*)d_in[4];
    const float* W_des = (const float*)d_in[5];  const float* b_des = (const float*)d_in[6];
    const float* W_tw  = (const float*)d_in[7];  const float* b_tw  = (const float*)d_in[8];
    const float* W_num = (const float*)d_in[9];  const float* b_num = (const float*)d_in[10];
    const float* W_cat = (const float*)d_in[11]; const float* b_cat = (const float*)d_in[12];
    const float* W_in  = (const float*)d_in[13]; const float* b_in  = (const float*)d_in[14];
    const float* W_g1  = (const float*)d_in[15]; const float* b_g1  = (const float*)d_in[16];
    const float* W_g2  = (const float*)d_in[17]; const float* b_g2  = (const float*)d_in[18];
    const float* W_o1  = (const float*)d_in[19]; const float* b_o1  = (const float*)d_in[20];
    const float* W_o2  = (const float*)d_in[21]; const float* b_o2  = (const float*)d_in[22];
    float* out = (float*)d_out;

    const int N = in_sizes[0] / 768;
    const int E = in_sizes[4] / 2;
    const int* src = eidx;
    const int* dst = eidx + E;

    const int NBUCK = (N + BNODES - 1) >> BSHIFT;    // <= 256 required
    const int CAP = (E / (NBUCK > 0 ? NBUCK : 1)) + (E / (NBUCK > 0 ? NBUCK : 1)) / 4 + 4096;

    // workspace layout
    char* ws = (char*)d_ws;
    const size_t szF = (size_t)N * HID * sizeof(float);
    float* F0 = (float*)ws;                    ws += szF;
    float* F1 = (float*)ws;                    ws += szF;
    float* F2 = (float*)ws;                    ws += szF;
    int* cnt      = (int*)ws;                  ws += ((size_t)N * 4 + 255) & ~255ULL;
    int* row_ptr  = (int*)ws;                  ws += (((size_t)N + 1) * 4 + 255) & ~255ULL;
    int* part     = (int*)ws;                  ws += 4096;
    float* dinv   = (float*)ws;                ws += ((size_t)N * 4 + 255) & ~255ULL;
    int* gcur     = (int*)ws;                  ws += 1024;
    const size_t sz768 = 768 * 32 * sizeof(short);
    const size_t sz128 = 128 * 128 * sizeof(short);
    short* wdes_hi = (short*)ws; ws += sz768;  short* wdes_lo = (short*)ws; ws += sz768;
    short* wtw_hi  = (short*)ws; ws += sz768;  short* wtw_lo  = (short*)ws; ws += sz768;
    short* win_hi  = (short*)ws; ws += sz128;  short* win_lo  = (short*)ws; ws += sz128;
    short* wg1_hi  = (short*)ws; ws += sz128;  short* wg1_lo  = (short*)ws; ws += sz128;
    short* wg2_hi  = (short*)ws; ws += sz128;  short* wg2_lo  = (short*)ws; ws += sz128;
    short* wo1_hi  = (short*)ws; ws += sz128;  short* wo1_lo  = (short*)ws; ws += sz128;
    int* col_idx  = (int*)ws;                  ws += ((size_t)E * 4 + 255) & ~255ULL;
    int2* pairs   = (int2*)ws;                 ws += (size_t)NBUCK * CAP * 8;

    const int B = (N + 255) / 256;

    // ---- weight fragment conversion ----
    {
        dim3 grid(12, 6);
        convert_w_kernel<<<grid, 256, 0, stream>>>(
            W_des, W_tw, W_in, W_g1, W_g2, W_o1,
            wdes_hi, wdes_lo, wtw_hi, wtw_lo, win_hi, win_lo,
            wg1_hi, wg1_lo, wg2_hi, wg2_lo, wo1_hi, wo1_lo);
    }

    // ---- CSR build (bucket partition, LDS-cursor scatter) ----
    hipMemsetAsync(gcur, 0, 1024, stream);
    hipMemsetAsync(cnt, 0, (size_t)N * sizeof(int), stream);
    partition_kernel<<<1024, 256, 0, stream>>>(src, dst, gcur, pairs, E, CAP);
    {
        dim3 hg(NBUCK, 2);
        hist_bucket_kernel<<<hg, 256, 0, stream>>>(pairs, gcur, cnt, CAP, N);
    }
    scan_block_kernel<<<B, 256, 0, stream>>>(cnt, row_ptr, part, N);
    scan_part_kernel<<<1, 512, 0, stream>>>(part, B);
    scan_final_kernel<<<(N + 256) / 256 + 1, 256, 0, stream>>>(row_ptr, part, cnt, dinv, N, B);
    scatter_lds_kernel<<<NBUCK, 512, 0, stream>>>(pairs, gcur, row_ptr, col_idx, CAP, N);

    // ---- encoder -> F0 (f32 x0) ----
    {
        dim3 grid((N + 63) / 64, 2);
        enc_lds_kernel<<<grid, 256, 0, stream>>>(des, tweet, wdes_hi, wdes_lo,
                                                 wtw_hi, wtw_lo, b_des, b_tw, F0, N);
        enc_nc_kernel<<<((size_t)N * 64 + 255) / 256, 256, 0, stream>>>(num, cat, W_num, b_num, W_cat, b_cat, F0, N);
    }

    // ---- fused x1+g1: F0 (f32) -> F2 (hs1 bf16) ----
    fused_x1g1_kernel<<<(N + 127) / 128, 512, 0, stream>>>(
        F0, win_hi, win_lo, b_in, wg1_hi, wg1_lo, dinv, (unsigned*)F2, N);

    // ---- fused conv1+g2: F2 -> F1 (hs2 bf16) ----
    fused_convgemm_kernel<false><<<(N + 31) / 32, 512, 0, stream>>>(
        (const unsigned*)F2, row_ptr, col_idx, dinv, b_g1,
        wg2_hi, wg2_lo, nullptr, nullptr, nullptr, F1, N);

    // ---- fused conv2+o1+out2: F1 -> out ----
    fused_convgemm_kernel<true><<<(N + 31) / 32, 512, 0, stream>>>(
        (const unsigned*)F1, row_ptr, col_idx, dinv, b_g2,
        wo1_hi, wo1_lo, b_o1, W_o2, b_o2, out, N);
}